// Round 14
// baseline (84.436 us; speedup 1.0000x reference)
//
#include <hip/hip_runtime.h>
#include <cfloat>
#include <climits>

#define NB 64
#define NA 2000
#define NAP 2048
#define NA0 1600
#define NC 20
#define NM 100

__device__ __forceinline__ void anchor_geom(int a, float& axc, float& ayc, float& st) {
    if (a < NA0) {
        st = 16.0f;
        int x = a % 40, y = a / 40;
        axc = ((float)x + 0.5f) * 16.0f;
        ayc = ((float)y + 0.5f) * 16.0f;
    } else {
        st = 32.0f;
        int aa = a - NA0;
        int x = aa % 20, y = aa / 20;
        axc = ((float)x + 0.5f) * 32.0f;
        ayc = ((float)y + 0.5f) * 32.0f;
    }
}

// SimOTA cost from precomputed pred extents/area; bit-identical to k_assign's inline form.
__device__ __forceinline__ float cost_row(const float4 g, float clsc, const float4 pe, float areaP,
                                          float axc, float ayc, float st, bool fc) {
    float glx = g.x - 0.5f * g.z, grx = g.x + 0.5f * g.z;
    float gty = g.y - 0.5f * g.w, gby = g.y + 0.5f * g.w;
    float tlx = fmaxf(glx, pe.x);
    float tly = fmaxf(gty, pe.z);
    float brx = fminf(grx, pe.y);
    float bry = fminf(gby, pe.w);
    float inter = (brx - tlx) * (bry - tly);
    bool ok = (tlx < brx) && (tly < bry);
    inter = ok ? inter : 0.0f;
    float iou = inter / ((g.z * g.w + areaP) - inter + 1e-16f);
    bool ib = (axc > glx) && (axc < grx) && (ayc > gty) && (ayc < gby);
    bool ic = (axc > g.x - 2.5f * st) && (axc < g.x + 2.5f * st)
           && (ayc > g.y - 2.5f * st) && (ayc < g.y + 2.5f * st);
    return ((clsc - 3.0f * __logf(iou + 1e-8f)) + ((ib && ic) ? 0.0f : 1e5f)) + (fc ? 0.0f : 1e9f);
}

// Wave64 u32 reduce via DPP; result to SGPR via readlane 63. HW-validated r5/r9-r13.
__device__ __forceinline__ unsigned int wave_max_u32(unsigned int x) {
    unsigned int y;
    y = (unsigned)__builtin_amdgcn_update_dpp((int)x, (int)x, 0x111, 0xf, 0xf, false); x = max(x, y);
    y = (unsigned)__builtin_amdgcn_update_dpp((int)x, (int)x, 0x112, 0xf, 0xf, false); x = max(x, y);
    y = (unsigned)__builtin_amdgcn_update_dpp((int)x, (int)x, 0x114, 0xf, 0xf, false); x = max(x, y);
    y = (unsigned)__builtin_amdgcn_update_dpp((int)x, (int)x, 0x118, 0xf, 0xf, false); x = max(x, y);
    y = (unsigned)__builtin_amdgcn_update_dpp((int)x, (int)x, 0x142, 0xa, 0xf, false); x = max(x, y);
    y = (unsigned)__builtin_amdgcn_update_dpp((int)x, (int)x, 0x143, 0xc, 0xf, false); x = max(x, y);
    return (unsigned)__builtin_amdgcn_readlane((int)x, 63);
}
__device__ __forceinline__ unsigned int wave_min_u32(unsigned int x) {
    unsigned int y;
    y = (unsigned)__builtin_amdgcn_update_dpp((int)x, (int)x, 0x111, 0xf, 0xf, false); x = min(x, y);
    y = (unsigned)__builtin_amdgcn_update_dpp((int)x, (int)x, 0x112, 0xf, 0xf, false); x = min(x, y);
    y = (unsigned)__builtin_amdgcn_update_dpp((int)x, (int)x, 0x114, 0xf, 0xf, false); x = min(x, y);
    y = (unsigned)__builtin_amdgcn_update_dpp((int)x, (int)x, 0x118, 0xf, 0xf, false); x = min(x, y);
    y = (unsigned)__builtin_amdgcn_update_dpp((int)x, (int)x, 0x142, 0xa, 0xf, false); x = min(x, y);
    y = (unsigned)__builtin_amdgcn_update_dpp((int)x, (int)x, 0x143, 0xc, 0xf, false); x = min(x, y);
    return (unsigned)__builtin_amdgcn_readlane((int)x, 63);
}

__global__ __launch_bounds__(256) void k_decode(const float* __restrict__ l0, const float* __restrict__ l1,
                                                const float* __restrict__ gt_boxes, const int* __restrict__ num_gts,
                                                float4* __restrict__ ext, float* __restrict__ decA,
                                                float* __restrict__ qq,
                                                unsigned long long* __restrict__ fgw, unsigned int* __restrict__ cm,
                                                float* __restrict__ sp) {
    int b = blockIdx.y;
    int a = blockIdx.x * 256 + threadIdx.x;   // 0..2047
    int lane = threadIdx.x & 63;
    __shared__ float4 sext[NM];   // gl, gr, gt, gb
    __shared__ float2 sctr[NM];   // g.x, g.y
    __shared__ int sng;
    if (threadIdx.x < NM) {
        float4 g = ((const float4*)gt_boxes)[b * NM + threadIdx.x];
        g.x *= 640.0f; g.y *= 640.0f; g.z *= 640.0f; g.w *= 640.0f;
        sext[threadIdx.x] = make_float4(g.x - 0.5f * g.z, g.x + 0.5f * g.z,
                                        g.y - 0.5f * g.w, g.y + 0.5f * g.w);
        sctr[threadIdx.x] = make_float2(g.x, g.y);
    }
    if (threadIdx.x == 0) sng = num_gts[b];
    __syncthreads();

    size_t pidx = (size_t)b * NAP + a;
    if (a >= NA) {
        // pad anchor: only cm must be defined (fc bit = 0 via real-lane ballot;
        // pad keys have zero IoU-value bits and >=1e9-or-NaN cost -> never selected;
        // validated r7-r13, absmax 0.25).
        cm[pidx] = 0;
        return;
    }

    float v[25];
    if (a < NA0) {
        const float* p = l0 + (size_t)b * 25 * NA0 + a;
#pragma unroll
        for (int c = 0; c < 25; c++) v[c] = p[(size_t)c * NA0];
    } else {
        const float* p = l1 + (size_t)b * 25 * 400 + (a - NA0);
#pragma unroll
        for (int c = 0; c < 25; c++) v[c] = p[(size_t)c * 400];
    }
    float axc, ayc, st;
    anchor_geom(a, axc, ayc, st);
    float gx, gy;
    if (a < NA0) { gx = (float)(a % 40); gy = (float)(a / 40); }
    else { int aa = a - NA0; gx = (float)(aa % 20); gy = (float)(aa / 20); }
    float4 pb;
    pb.x = (v[0] + gx) * st;
    pb.y = (v[1] + gy) * st;
    pb.z = expf(v[2]) * st;
    pb.w = expf(v[3]) * st;
    ext[pidx] = make_float4(pb.x - 0.5f * pb.z, pb.x + 0.5f * pb.z,
                            pb.y - 0.5f * pb.w, pb.y + 0.5f * pb.w);
    decA[pidx] = pb.z * pb.w;

    float sob = 1.0f / (1.0f + __expf(-v[4]));
    float d[NC];
    float s = 0.0f;
    float spv = 0.0f;
#pragma unroll
    for (int c = 0; c < NC; c++) {
        float x = v[5 + c];
        float sc = 1.0f / (1.0f + __expf(-x));
        float p = sqrtf(sc * sob);
        float lp = __logf(p + 1e-12f);
        float lq = __logf(1.0f - p + 1e-12f);
        s += -lq;
        d[c] = lq - lp;
        spv += fmaxf(x, 0.0f) + log1pf(__expf(-fabsf(x)));   // softplus sum (class order)
    }
#pragma unroll
    for (int c = 0; c < NC; c++)
        qq[((size_t)b * NC + c) * NAP + a] = s + d[c];
    sp[pidx] = spv;

    int ng = sng;
    int f = 0;
    float rst = 2.5f * st;
    for (int m = 0; m < ng; m++) {
        float4 e = sext[m];
        float2 cc = sctr[m];
        bool ib = (axc > e.x) && (axc < e.y) && (ayc > e.z) && (ayc < e.w);
        bool ic = (axc > cc.x - rst) && (axc < cc.x + rst) && (ayc > cc.y - rst) && (ayc < cc.y + rst);
        if (ib || ic) { f = 1; break; }
    }
    unsigned long long mk = __ballot(f);
    if (lane == 0) fgw[(size_t)b * 32 + (a >> 6)] = mk;
    cm[pidx] = 0;
}

// TWO waves per (b, m) row (j-halves of 16), 4 waves = 2 rows per block —
// the r10/r11 sweet spot (r13's 4-wave split cost ~4us in barrier/merge
// overhead). Local destructive extraction on 16-reg trees; global top-k via
// 2-way merge of sorted local lists in LDS. Key semantics = r9-r13.
__global__ __launch_bounds__(256) void k_assign(const float* __restrict__ gt_boxes, const int* __restrict__ gt_classes,
                                                const int* __restrict__ num_gts, const float4* __restrict__ ext,
                                                const float* __restrict__ decA,
                                                const float* __restrict__ qq, const unsigned long long* __restrict__ fgw,
                                                unsigned int* __restrict__ cm) {
    int lane = threadIdx.x & 63;
    int wv = __builtin_amdgcn_readfirstlane((int)(threadIdx.x >> 6));
    int rloc = wv >> 1, half = wv & 1;
    int row = __builtin_amdgcn_readfirstlane((int)(blockIdx.x * 2 + rloc));
    int b = row / NM, m = row - b * NM;
    bool valid = (m < num_gts[b]);

    __shared__ unsigned int lA[2][2][10];   // [row][half][k] descending iou keys
    __shared__ unsigned int lB[2][2][10];   // [row][half][k] ascending cost keys
    __shared__ unsigned int lmeta[2];       // dk per row
    __shared__ unsigned int lthr[2];        // threshold key per row

    unsigned int ik[16], ck[16];
    size_t bNA = (size_t)b * NAP;
    unsigned int inc = (1u << 20) + (unsigned)m;

    if (valid) {
        float4 g = ((const float4*)gt_boxes)[b * NM + m];
        g.x *= 640.0f; g.y *= 640.0f; g.z *= 640.0f; g.w *= 640.0f;
        int tc = gt_classes[b * NM + m];
        const float* qrow = qq + ((size_t)b * NC + tc) * NAP;

        float glx = g.x - 0.5f * g.z, grx = g.x + 0.5f * g.z;
        float gty = g.y - 0.5f * g.w, gby = g.y + 0.5f * g.w;
        float areag = g.z * g.w;
        float c16l = g.x - 40.0f, c16r = g.x + 40.0f, c16t = g.y - 40.0f, c16b = g.y + 40.0f;
        float c32l = g.x - 80.0f, c32r = g.x + 80.0f, c32t = g.y - 80.0f, c32b = g.y + 80.0f;

#pragma unroll
        for (int j = 0; j < 16; j++) {
            int jj = half * 16 + j;
            int a = jj * 64 + lane;
            bool lvl0 = jj < 25;
            float stj = lvl0 ? 16.0f : 32.0f;
            // constant-divisor divides (magic mul), then select; unselected
            // branch may divide a negative value — well-defined, discarded.
            int y40 = a / 40;
            int aa2 = a - NA0;
            int y20 = aa2 / 20;
            int gyv = lvl0 ? y40 : y20;
            int gxv = lvl0 ? (a - y40 * 40) : (aa2 - y20 * 20);
            float axc = ((float)gxv + 0.5f) * stj;
            float ayc = ((float)gyv + 0.5f) * stj;
            unsigned long long fw = fgw[(size_t)b * 32 + jj];
            bool fc = (fw >> lane) & 1ULL;
            float4 pe = ext[bNA + a];
            float areaP = decA[bNA + a];
            float clsc = qrow[a];
            float tlx = fmaxf(glx, pe.x);
            float tly = fmaxf(gty, pe.z);
            float brx = fminf(grx, pe.y);
            float bry = fminf(gby, pe.w);
            float inter = (brx - tlx) * (bry - tly);
            bool ok = (tlx < brx) && (tly < bry);
            inter = ok ? inter : 0.0f;
            float iou = inter / ((areag + areaP) - inter + 1e-16f);
            bool ib = (axc > glx) && (axc < grx) && (ayc > gty) && (ayc < gby);
            bool ic = lvl0 ? ((axc > c16l) && (axc < c16r) && (ayc > c16t) && (ayc < c16b))
                           : ((axc > c32l) && (axc < c32r) && (ayc > c32t) && (ayc < c32b));
            float cc = ((clsc - 3.0f * __logf(iou + 1e-8f)) + ((ib && ic) ? 0.0f : 1e5f)) + (fc ? 0.0f : 1e9f);
            float im = fc ? iou : 0.0f;
            ik[j] = (__float_as_uint(im) & 0xFFFFF800u) | (unsigned)a;
            ck[j] = (__float_as_uint(cc) & 0xFFFFF800u) | (unsigned)a;
        }

        // Phase A local: up to 10 destructive max-extractions; pad with 0-keys on early break.
        int k = 0;
#pragma unroll 1
        for (; k < 10; ++k) {
            unsigned int t[8];
#pragma unroll
            for (int h = 0; h < 8; h++) t[h] = max(ik[2 * h], ik[2 * h + 1]);
#pragma unroll
            for (int w = 4; w >= 1; w >>= 1)
#pragma unroll
                for (int h = 0; h < w; h++) t[h] = max(t[h], t[h + w]);
            unsigned int mx = wave_max_u32(t[0]);
            if ((mx & 0xFFFFF800u) == 0u) break;
            if (lane == 0) lA[rloc][half][k] = mx;
#pragma unroll
            for (int j = 0; j < 16; j++) ik[j] = (ik[j] == mx) ? 0u : ik[j];
        }
#pragma unroll 1
        for (; k < 10; ++k) if (lane == 0) lA[rloc][half][k] = 0u;
    }
    __syncthreads();

    // Merge A (one lane per row): global top-10 sum in descending order -> dk.
    if (valid && half == 0 && lane == 0) {
        int i0 = 0, i1 = 0;
        float s = 0.0f;
        for (int k = 0; k < 10; k++) {
            unsigned int a0 = lA[rloc][0][i0], a1 = lA[rloc][1][i1];
            unsigned int mx;
            if (a1 > a0) { mx = a1; i1++; } else { mx = a0; i0++; }
            s += __uint_as_float(mx & 0xFFFFF800u);
        }
        int dk = (int)s;
        if (dk < 1) dk = 1;
        lmeta[rloc] = (unsigned)dk;
    }
    __syncthreads();

    int dkv = 0;
    if (valid) dkv = __builtin_amdgcn_readfirstlane((int)lmeta[rloc]);

    // Phase B local: dk destructive min-extractions into LDS.
    if (valid) {
#pragma unroll 1
        for (int k = 0; k < dkv; k++) {
            unsigned int t[8];
#pragma unroll
            for (int h = 0; h < 8; h++) t[h] = min(ck[2 * h], ck[2 * h + 1]);
#pragma unroll
            for (int w = 4; w >= 1; w >>= 1)
#pragma unroll
                for (int h = 0; h < w; h++) t[h] = min(t[h], t[h + w]);
            unsigned int mn = wave_min_u32(t[0]);
            if (lane == 0) lB[rloc][half][k] = mn;
#pragma unroll
            for (int j = 0; j < 16; j++) ck[j] = (ck[j] == mn) ? 0xFFFFFFFFu : ck[j];
        }
    }
    __syncthreads();

    // Merge B: dk-th smallest of the union = threshold key.
    if (valid && half == 0 && lane == 0) {
        int i0 = 0, i1 = 0;
        unsigned int thr = 0;
        for (int k = 0; k < dkv; k++) {
            unsigned int a0 = lB[rloc][0][i0], a1 = lB[rloc][1][i1];
            if (a1 < a0) { thr = a1; i1++; } else { thr = a0; i0++; }
        }
        lthr[rloc] = thr;
    }
    __syncthreads();

    if (valid) {
        unsigned int thr = (unsigned)__builtin_amdgcn_readfirstlane((int)lthr[rloc]);
        unsigned int mb = 0;
        // survivors: key <= thr (destroyed are 0xFFFFFFFF > thr; keys unique)
#pragma unroll
        for (int j = 0; j < 16; j++) if (ck[j] <= thr) mb |= 1u << j;
        // recovered: my wave's extracted keys from LDS
#pragma unroll 1
        for (int k = 0; k < dkv; k++) {
            unsigned int e = lB[rloc][half][k];
            if (e <= thr) {
                unsigned int idx = e & 0x7FFu;
                if ((int)(idx & 63u) == lane) mb |= 1u << ((int)(idx >> 6) - half * 16);
            }
        }
#pragma unroll
        for (int j = 0; j < 16; j++) {
            if ((mb >> j) & 1u) atomicAdd(&cm[bNA + (size_t)(half * 16 + j) * 64 + lane], inc);
        }
    }
}

// Fused conflict-resolution + loss kernel over the PADDED index space
// (waves never straddle images). No device-scope fences (r12 lesson).
__global__ __launch_bounds__(256) void k_resolve(const float* __restrict__ l0, const float* __restrict__ l1,
                                                 const float* __restrict__ gt_boxes, const int* __restrict__ gt_classes,
                                                 const int* __restrict__ num_gts,
                                                 const float4* __restrict__ ext, const float* __restrict__ decA,
                                                 const float* __restrict__ qq, const unsigned long long* __restrict__ fgw,
                                                 const unsigned int* __restrict__ cm,
                                                 const float* __restrict__ sp,
                                                 float* __restrict__ partials) {
    int gtid = blockIdx.x * 256 + threadIdx.x;   // padded 0 .. 64*2048-1
    int lane = threadIdx.x & 63;
    int b = gtid >> 11;
    int a = gtid & (NAP - 1);
    bool real = a < NA;

    unsigned int word = real ? cm[gtid] : 0u;
    int mres = (int)(word & 0xFFFFFu);

    unsigned long long msk = __ballot((word >> 20) >= 2u);
    if (msk != 0ull) {
        int base = gtid & ~63;
        int ng = num_gts[b];
        while (msk) {
            int t = __ffsll((long long)msk) - 1;
            msk &= msk - 1;
            int idx = base + t;
            int aa = idx & (NAP - 1);
            float4 pe = ext[idx];
            float areaP = decA[idx];
            float axc, ayc, st;
            anchor_geom(aa, axc, ayc, st);
            bool fcq = (fgw[(size_t)b * 32 + (aa >> 6)] >> (aa & 63)) & 1ULL;
            unsigned int best = 0xFFFFFFFFu;
#pragma unroll
            for (int half = 0; half < 2; half++) {
                int m = half * 64 + lane;
                if (m < ng) {
                    float4 g = ((const float4*)gt_boxes)[b * NM + m];
                    g.x *= 640.0f; g.y *= 640.0f; g.z *= 640.0f; g.w *= 640.0f;
                    int tcm = gt_classes[b * NM + m];
                    float clsc = qq[((size_t)b * NC + tcm) * NAP + aa];
                    float cc = cost_row(g, clsc, pe, areaP, axc, ayc, st, fcq);
                    unsigned int key = (__float_as_uint(cc) & 0xFFFFF800u) | (unsigned)m;
                    best = min(best, key);
                }
            }
#pragma unroll
            for (int o = 1; o < 64; o <<= 1) {
                unsigned int ov = (unsigned int)__shfl_xor((int)best, o);
                best = min(best, ov);
            }
            if (lane == t) mres = (int)(best & 0x7FFu);
        }
    }

    float lobj = 0.0f, liou = 0.0f, lcls = 0.0f, fgf = 0.0f;
    if (real) {
        float objv;
        if (a < NA0) objv = l0[((size_t)b * 25 + 4) * NA0 + a];
        else         objv = l1[((size_t)b * 25 + 4) * 400 + (a - NA0)];
        bool fg = (word >> 20) > 0;
        fgf = fg ? 1.0f : 0.0f;
        lobj = (fmaxf(objv, 0.0f) + log1pf(expf(-fabsf(objv)))) - objv * fgf;
        if (fg) {
            float4 pe = ext[gtid];
            float areaP = decA[gtid];
            int m = mres;
            float4 g = ((const float4*)gt_boxes)[b * NM + m];
            g.x *= 640.0f; g.y *= 640.0f; g.z *= 640.0f; g.w *= 640.0f;
            float tlx = fmaxf(pe.x, g.x - 0.5f * g.z);
            float tly = fmaxf(pe.z, g.y - 0.5f * g.w);
            float brx = fminf(pe.y, g.x + 0.5f * g.z);
            float bry = fminf(pe.w, g.y + 0.5f * g.w);
            float inter = (brx - tlx) * (bry - tly);
            bool ok = (tlx < brx) && (tly < bry);
            inter = ok ? inter : 0.0f;
            float iou = inter / ((areaP + g.z * g.w) - inter + 1e-16f);
            liou = 1.0f - iou * iou;
            float piou = iou;
            int tcm = gt_classes[b * NM + m];
            float x_t;
            if (a < NA0) x_t = l0[((size_t)b * 25 + 5 + tcm) * NA0 + a];
            else         x_t = l1[((size_t)b * 25 + 5 + tcm) * 400 + (a - NA0)];
            lcls = sp[gtid] - x_t * piou;   // sum_c softplus(x_c) - x_tcm * pred_iou
        }
    }

    __shared__ float s0[256], s1[256], s2[256], s3[256];
    int t = threadIdx.x;
    s0[t] = lobj; s1[t] = liou; s2[t] = lcls; s3[t] = fgf;
    __syncthreads();
    for (int o = 128; o > 0; o >>= 1) {
        if (t < o) { s0[t] += s0[t + o]; s1[t] += s1[t + o]; s2[t] += s2[t + o]; s3[t] += s3[t + o]; }
        __syncthreads();
    }
    if (t == 0) {
        partials[blockIdx.x * 4 + 0] = s0[0];
        partials[blockIdx.x * 4 + 1] = s1[0];
        partials[blockIdx.x * 4 + 2] = s2[0];
        partials[blockIdx.x * 4 + 3] = s3[0];
    }
}

__global__ __launch_bounds__(256) void k_final(const float* __restrict__ partials, int nblocks,
                                               const int* __restrict__ num_gts, float* __restrict__ out) {
    __shared__ float s0[256], s1[256], s2[256], s3[256];
    int t = threadIdx.x;
    float a0 = 0, a1 = 0, a2 = 0, a3 = 0;
    for (int i = t; i < nblocks; i += 256) {
        a0 += partials[i * 4 + 0];
        a1 += partials[i * 4 + 1];
        a2 += partials[i * 4 + 2];
        a3 += partials[i * 4 + 3];
    }
    s0[t] = a0; s1[t] = a1; s2[t] = a2; s3[t] = a3;
    __syncthreads();
    for (int o = 128; o > 0; o >>= 1) {
        if (t < o) { s0[t] += s0[t + o]; s1[t] += s1[t + o]; s2[t] += s2[t + o]; s3[t] += s3[t + o]; }
        __syncthreads();
    }
    if (t == 0) {
        int sg = 0;
        for (int i = 0; i < NB; i++) sg += num_gts[i];
        float num_fg = fmaxf(s3[0], 1.0f);
        float li5 = 5.0f * (s1[0] / num_fg);
        float lo = s0[0] / num_fg;
        float lcx = s2[0] / num_fg;
        out[0] = li5 + lo + lcx;
        out[1] = li5;
        out[2] = lo;
        out[3] = lcx;
        out[4] = num_fg / fmaxf((float)sg, 1.0f);
    }
}

extern "C" void kernel_launch(void* const* d_in, const int* in_sizes, int n_in,
                              void* d_out, int out_size, void* d_ws, size_t ws_size,
                              hipStream_t stream) {
    const float* l0 = (const float*)d_in[0];
    const float* l1 = (const float*)d_in[1];
    const float* gt_boxes = (const float*)d_in[2];
    const int* gt_classes = (const int*)d_in[3];
    const int* num_gts = (const int*)d_in[4];
    float* out = (float*)d_out;

    char* w = (char*)d_ws;
    float4* ext  = (float4*)(w);                           // 64*2048*16 = 2,097,152
    float* decA  = (float*)(w + 2097152);                  // 64*2048*4 = 524,288
    float* qq    = (float*)(w + 2621440);                  // 64*20*2048*4 = 10,485,760
    unsigned long long* fgw = (unsigned long long*)(w + 13107200); // 16,384
    unsigned int* cm = (unsigned int*)(w + 13123584);      // 64*2048*4 = 524,288
    float* sp    = (float*)(w + 13647872);                 // 64*2048*4 = 524,288
    float* partials = (float*)(w + 14172160);              // 512*4*4 = 8,192

    (void)n_in; (void)in_sizes; (void)out_size; (void)ws_size;

    k_decode<<<dim3(8, NB), 256, 0, stream>>>(l0, l1, gt_boxes, num_gts, ext, decA, qq, fgw, cm, sp);
    k_assign<<<(NB * NM) / 2, 256, 0, stream>>>(gt_boxes, gt_classes, num_gts, ext, decA, qq, fgw, cm);
    k_resolve<<<(NB * NAP) / 256, 256, 0, stream>>>(l0, l1, gt_boxes, gt_classes, num_gts, ext, decA, qq, fgw, cm, sp, partials);
    k_final<<<1, 256, 0, stream>>>(partials, (NB * NAP) / 256, num_gts, out);
}

// Round 15
// 72.618 us; speedup vs baseline: 1.1627x; 1.1627x over previous
//
#include <hip/hip_runtime.h>
#include <cfloat>
#include <climits>

#define NB 64
#define NA 2000
#define NAP 2048
#define NA0 1600
#define NC 20
#define NM 100

__device__ __forceinline__ void anchor_geom(int a, float& axc, float& ayc, float& st) {
    if (a < NA0) {
        st = 16.0f;
        int x = a % 40, y = a / 40;
        axc = ((float)x + 0.5f) * 16.0f;
        ayc = ((float)y + 0.5f) * 16.0f;
    } else {
        st = 32.0f;
        int aa = a - NA0;
        int x = aa % 20, y = aa / 20;
        axc = ((float)x + 0.5f) * 32.0f;
        ayc = ((float)y + 0.5f) * 32.0f;
    }
}

// SimOTA cost from precomputed pred extents/area; bit-identical to k_assign's inline form.
__device__ __forceinline__ float cost_row(const float4 g, float clsc, const float4 pe, float areaP,
                                          float axc, float ayc, float st, bool fc) {
    float glx = g.x - 0.5f * g.z, grx = g.x + 0.5f * g.z;
    float gty = g.y - 0.5f * g.w, gby = g.y + 0.5f * g.w;
    float tlx = fmaxf(glx, pe.x);
    float tly = fmaxf(gty, pe.z);
    float brx = fminf(grx, pe.y);
    float bry = fminf(gby, pe.w);
    float inter = (brx - tlx) * (bry - tly);
    bool ok = (tlx < brx) && (tly < bry);
    inter = ok ? inter : 0.0f;
    float iou = inter / ((g.z * g.w + areaP) - inter + 1e-16f);
    bool ib = (axc > glx) && (axc < grx) && (ayc > gty) && (ayc < gby);
    bool ic = (axc > g.x - 2.5f * st) && (axc < g.x + 2.5f * st)
           && (ayc > g.y - 2.5f * st) && (ayc < g.y + 2.5f * st);
    return ((clsc - 3.0f * __logf(iou + 1e-8f)) + ((ib && ic) ? 0.0f : 1e5f)) + (fc ? 0.0f : 1e9f);
}

// Wave64 u32 reduce via DPP; result to SGPR via readlane 63. HW-validated r5/r9-r14.
__device__ __forceinline__ unsigned int wave_max_u32(unsigned int x) {
    unsigned int y;
    y = (unsigned)__builtin_amdgcn_update_dpp((int)x, (int)x, 0x111, 0xf, 0xf, false); x = max(x, y);
    y = (unsigned)__builtin_amdgcn_update_dpp((int)x, (int)x, 0x112, 0xf, 0xf, false); x = max(x, y);
    y = (unsigned)__builtin_amdgcn_update_dpp((int)x, (int)x, 0x114, 0xf, 0xf, false); x = max(x, y);
    y = (unsigned)__builtin_amdgcn_update_dpp((int)x, (int)x, 0x118, 0xf, 0xf, false); x = max(x, y);
    y = (unsigned)__builtin_amdgcn_update_dpp((int)x, (int)x, 0x142, 0xa, 0xf, false); x = max(x, y);
    y = (unsigned)__builtin_amdgcn_update_dpp((int)x, (int)x, 0x143, 0xc, 0xf, false); x = max(x, y);
    return (unsigned)__builtin_amdgcn_readlane((int)x, 63);
}
__device__ __forceinline__ unsigned int wave_min_u32(unsigned int x) {
    unsigned int y;
    y = (unsigned)__builtin_amdgcn_update_dpp((int)x, (int)x, 0x111, 0xf, 0xf, false); x = min(x, y);
    y = (unsigned)__builtin_amdgcn_update_dpp((int)x, (int)x, 0x112, 0xf, 0xf, false); x = min(x, y);
    y = (unsigned)__builtin_amdgcn_update_dpp((int)x, (int)x, 0x114, 0xf, 0xf, false); x = min(x, y);
    y = (unsigned)__builtin_amdgcn_update_dpp((int)x, (int)x, 0x118, 0xf, 0xf, false); x = min(x, y);
    y = (unsigned)__builtin_amdgcn_update_dpp((int)x, (int)x, 0x142, 0xa, 0xf, false); x = min(x, y);
    y = (unsigned)__builtin_amdgcn_update_dpp((int)x, (int)x, 0x143, 0xc, 0xf, false); x = min(x, y);
    return (unsigned)__builtin_amdgcn_readlane((int)x, 63);
}

__global__ __launch_bounds__(256) void k_decode(const float* __restrict__ l0, const float* __restrict__ l1,
                                                const float* __restrict__ gt_boxes, const int* __restrict__ num_gts,
                                                float4* __restrict__ ext, float* __restrict__ decA,
                                                float* __restrict__ qq,
                                                unsigned long long* __restrict__ fgw, unsigned int* __restrict__ cm,
                                                float* __restrict__ sp) {
    int b = blockIdx.y;
    int a = blockIdx.x * 256 + threadIdx.x;   // 0..2047
    int lane = threadIdx.x & 63;
    __shared__ float4 sext[NM];   // gl, gr, gt, gb
    __shared__ float2 sctr[NM];   // g.x, g.y
    __shared__ int sng;
    if (threadIdx.x < NM) {
        float4 g = ((const float4*)gt_boxes)[b * NM + threadIdx.x];
        g.x *= 640.0f; g.y *= 640.0f; g.z *= 640.0f; g.w *= 640.0f;
        sext[threadIdx.x] = make_float4(g.x - 0.5f * g.z, g.x + 0.5f * g.z,
                                        g.y - 0.5f * g.w, g.y + 0.5f * g.w);
        sctr[threadIdx.x] = make_float2(g.x, g.y);
    }
    if (threadIdx.x == 0) sng = num_gts[b];
    __syncthreads();

    size_t pidx = (size_t)b * NAP + a;
    if (a >= NA) {
        // pad anchor: only cm must be defined (fc bit = 0 via real-lane ballot;
        // pad keys have zero IoU-value bits and >=1e9-or-NaN cost -> never selected;
        // validated r7-r14, absmax 0.25).
        cm[pidx] = 0;
        return;
    }

    float v[25];
    if (a < NA0) {
        const float* p = l0 + (size_t)b * 25 * NA0 + a;
#pragma unroll
        for (int c = 0; c < 25; c++) v[c] = p[(size_t)c * NA0];
    } else {
        const float* p = l1 + (size_t)b * 25 * 400 + (a - NA0);
#pragma unroll
        for (int c = 0; c < 25; c++) v[c] = p[(size_t)c * 400];
    }
    float axc, ayc, st;
    anchor_geom(a, axc, ayc, st);
    float gx, gy;
    if (a < NA0) { gx = (float)(a % 40); gy = (float)(a / 40); }
    else { int aa = a - NA0; gx = (float)(aa % 20); gy = (float)(aa / 20); }
    float4 pb;
    pb.x = (v[0] + gx) * st;
    pb.y = (v[1] + gy) * st;
    pb.z = expf(v[2]) * st;
    pb.w = expf(v[3]) * st;
    ext[pidx] = make_float4(pb.x - 0.5f * pb.z, pb.x + 0.5f * pb.z,
                            pb.y - 0.5f * pb.w, pb.y + 0.5f * pb.w);
    decA[pidx] = pb.z * pb.w;

    float sob = 1.0f / (1.0f + __expf(-v[4]));
    float d[NC];
    float s = 0.0f;
    float spv = 0.0f;
#pragma unroll
    for (int c = 0; c < NC; c++) {
        float x = v[5 + c];
        float sc = 1.0f / (1.0f + __expf(-x));
        float p = sqrtf(sc * sob);
        float lp = __logf(p + 1e-12f);
        float lq = __logf(1.0f - p + 1e-12f);
        s += -lq;
        d[c] = lq - lp;
        spv += fmaxf(x, 0.0f) + log1pf(__expf(-fabsf(x)));   // softplus sum (class order)
    }
#pragma unroll
    for (int c = 0; c < NC; c++)
        qq[((size_t)b * NC + c) * NAP + a] = s + d[c];
    sp[pidx] = spv;

    int ng = sng;
    int f = 0;
    float rst = 2.5f * st;
    for (int m = 0; m < ng; m++) {
        float4 e = sext[m];
        float2 cc = sctr[m];
        bool ib = (axc > e.x) && (axc < e.y) && (ayc > e.z) && (ayc < e.w);
        bool ic = (axc > cc.x - rst) && (axc < cc.x + rst) && (ayc > cc.y - rst) && (ayc < cc.y + rst);
        if (ib || ic) { f = 1; break; }
    }
    unsigned long long mk = __ballot(f);
    if (lane == 0) fgw[(size_t)b * 32 + (a >> 6)] = mk;
    cm[pidx] = 0;
}

// TWO waves per (b, m) row (j-halves of 16), 4 waves = 2 rows per block —
// the measured sweet spot (1-wave r9: latency-bound; 4-wave r13: barrier
// overhead). Local destructive extraction on 16-reg trees; global top-k via
// 2-way merge of sorted local lists in LDS. Key semantics = r9-r14.
__global__ __launch_bounds__(256) void k_assign(const float* __restrict__ gt_boxes, const int* __restrict__ gt_classes,
                                                const int* __restrict__ num_gts, const float4* __restrict__ ext,
                                                const float* __restrict__ decA,
                                                const float* __restrict__ qq, const unsigned long long* __restrict__ fgw,
                                                unsigned int* __restrict__ cm) {
    int lane = threadIdx.x & 63;
    int wv = __builtin_amdgcn_readfirstlane((int)(threadIdx.x >> 6));
    int rloc = wv >> 1, half = wv & 1;
    int row = __builtin_amdgcn_readfirstlane((int)(blockIdx.x * 2 + rloc));
    int b = row / NM, m = row - b * NM;
    bool valid = (m < num_gts[b]);

    __shared__ unsigned int lA[2][2][10];   // [row][half][k] descending iou keys
    __shared__ unsigned int lB[2][2][10];   // [row][half][k] ascending cost keys
    __shared__ unsigned int lmeta[2];       // dk per row
    __shared__ unsigned int lthr[2];        // threshold key per row

    unsigned int ik[16], ck[16];
    size_t bNA = (size_t)b * NAP;
    unsigned int inc = (1u << 20) + (unsigned)m;

    if (valid) {
        float4 g = ((const float4*)gt_boxes)[b * NM + m];
        g.x *= 640.0f; g.y *= 640.0f; g.z *= 640.0f; g.w *= 640.0f;
        int tc = gt_classes[b * NM + m];
        const float* qrow = qq + ((size_t)b * NC + tc) * NAP;

        float glx = g.x - 0.5f * g.z, grx = g.x + 0.5f * g.z;
        float gty = g.y - 0.5f * g.w, gby = g.y + 0.5f * g.w;
        float areag = g.z * g.w;
        float c16l = g.x - 40.0f, c16r = g.x + 40.0f, c16t = g.y - 40.0f, c16b = g.y + 40.0f;
        float c32l = g.x - 80.0f, c32r = g.x + 80.0f, c32t = g.y - 80.0f, c32b = g.y + 80.0f;

#pragma unroll
        for (int j = 0; j < 16; j++) {
            int jj = half * 16 + j;
            int a = jj * 64 + lane;
            bool lvl0 = jj < 25;
            float stj = lvl0 ? 16.0f : 32.0f;
            int rel = lvl0 ? a : (a - NA0);
            int W = lvl0 ? 40 : 20;
            int gyv = rel / W;
            int gxv = rel - gyv * W;
            float axc = ((float)gxv + 0.5f) * stj;
            float ayc = ((float)gyv + 0.5f) * stj;
            unsigned long long fw = fgw[(size_t)b * 32 + jj];
            bool fc = (fw >> lane) & 1ULL;
            float4 pe = ext[bNA + a];
            float areaP = decA[bNA + a];
            float clsc = qrow[a];
            float tlx = fmaxf(glx, pe.x);
            float tly = fmaxf(gty, pe.z);
            float brx = fminf(grx, pe.y);
            float bry = fminf(gby, pe.w);
            float inter = (brx - tlx) * (bry - tly);
            bool ok = (tlx < brx) && (tly < bry);
            inter = ok ? inter : 0.0f;
            float iou = inter / ((areag + areaP) - inter + 1e-16f);
            bool ib = (axc > glx) && (axc < grx) && (ayc > gty) && (ayc < gby);
            bool ic = lvl0 ? ((axc > c16l) && (axc < c16r) && (ayc > c16t) && (ayc < c16b))
                           : ((axc > c32l) && (axc < c32r) && (ayc > c32t) && (ayc < c32b));
            float cc = ((clsc - 3.0f * __logf(iou + 1e-8f)) + ((ib && ic) ? 0.0f : 1e5f)) + (fc ? 0.0f : 1e9f);
            float im = fc ? iou : 0.0f;
            ik[j] = (__float_as_uint(im) & 0xFFFFF800u) | (unsigned)a;
            ck[j] = (__float_as_uint(cc) & 0xFFFFF800u) | (unsigned)a;
        }

        // Phase A local: up to 10 destructive max-extractions; pad with 0-keys on early break.
        int k = 0;
#pragma unroll 1
        for (; k < 10; ++k) {
            unsigned int t[8];
#pragma unroll
            for (int h = 0; h < 8; h++) t[h] = max(ik[2 * h], ik[2 * h + 1]);
#pragma unroll
            for (int w = 4; w >= 1; w >>= 1)
#pragma unroll
                for (int h = 0; h < w; h++) t[h] = max(t[h], t[h + w]);
            unsigned int mx = wave_max_u32(t[0]);
            if ((mx & 0xFFFFF800u) == 0u) break;
            if (lane == 0) lA[rloc][half][k] = mx;
#pragma unroll
            for (int j = 0; j < 16; j++) ik[j] = (ik[j] == mx) ? 0u : ik[j];
        }
#pragma unroll 1
        for (; k < 10; ++k) if (lane == 0) lA[rloc][half][k] = 0u;
    }
    __syncthreads();

    // Merge A (one lane per row): global top-10 sum in descending order -> dk.
    if (valid && half == 0 && lane == 0) {
        int i0 = 0, i1 = 0;
        float s = 0.0f;
        for (int k = 0; k < 10; k++) {
            unsigned int a0 = lA[rloc][0][i0], a1 = lA[rloc][1][i1];
            unsigned int mx;
            if (a1 > a0) { mx = a1; i1++; } else { mx = a0; i0++; }
            s += __uint_as_float(mx & 0xFFFFF800u);
        }
        int dk = (int)s;
        if (dk < 1) dk = 1;
        lmeta[rloc] = (unsigned)dk;
    }
    __syncthreads();

    int dkv = 0;
    if (valid) dkv = __builtin_amdgcn_readfirstlane((int)lmeta[rloc]);

    // Phase B local: dk destructive min-extractions into LDS.
    if (valid) {
#pragma unroll 1
        for (int k = 0; k < dkv; k++) {
            unsigned int t[8];
#pragma unroll
            for (int h = 0; h < 8; h++) t[h] = min(ck[2 * h], ck[2 * h + 1]);
#pragma unroll
            for (int w = 4; w >= 1; w >>= 1)
#pragma unroll
                for (int h = 0; h < w; h++) t[h] = min(t[h], t[h + w]);
            unsigned int mn = wave_min_u32(t[0]);
            if (lane == 0) lB[rloc][half][k] = mn;
#pragma unroll
            for (int j = 0; j < 16; j++) ck[j] = (ck[j] == mn) ? 0xFFFFFFFFu : ck[j];
        }
    }
    __syncthreads();

    // Merge B: dk-th smallest of the union = threshold key.
    if (valid && half == 0 && lane == 0) {
        int i0 = 0, i1 = 0;
        unsigned int thr = 0;
        for (int k = 0; k < dkv; k++) {
            unsigned int a0 = lB[rloc][0][i0], a1 = lB[rloc][1][i1];
            if (a1 < a0) { thr = a1; i1++; } else { thr = a0; i0++; }
        }
        lthr[rloc] = thr;
    }
    __syncthreads();

    if (valid) {
        unsigned int thr = (unsigned)__builtin_amdgcn_readfirstlane((int)lthr[rloc]);
        unsigned int mb = 0;
        // survivors: key <= thr (destroyed are 0xFFFFFFFF > thr; keys unique)
#pragma unroll
        for (int j = 0; j < 16; j++) if (ck[j] <= thr) mb |= 1u << j;
        // recovered: my wave's extracted keys from LDS
#pragma unroll 1
        for (int k = 0; k < dkv; k++) {
            unsigned int e = lB[rloc][half][k];
            if (e <= thr) {
                unsigned int idx = e & 0x7FFu;
                if ((int)(idx & 63u) == lane) mb |= 1u << ((int)(idx >> 6) - half * 16);
            }
        }
#pragma unroll
        for (int j = 0; j < 16; j++) {
            if ((mb >> j) & 1u) atomicAdd(&cm[bNA + (size_t)(half * 16 + j) * 64 + lane], inc);
        }
    }
}

// Fused conflict-resolution + loss kernel over the PADDED index space
// (waves never straddle images). No device-scope fences (r12 lesson).
__global__ __launch_bounds__(256) void k_resolve(const float* __restrict__ l0, const float* __restrict__ l1,
                                                 const float* __restrict__ gt_boxes, const int* __restrict__ gt_classes,
                                                 const int* __restrict__ num_gts,
                                                 const float4* __restrict__ ext, const float* __restrict__ decA,
                                                 const float* __restrict__ qq, const unsigned long long* __restrict__ fgw,
                                                 const unsigned int* __restrict__ cm,
                                                 const float* __restrict__ sp,
                                                 float* __restrict__ partials) {
    int gtid = blockIdx.x * 256 + threadIdx.x;   // padded 0 .. 64*2048-1
    int lane = threadIdx.x & 63;
    int b = gtid >> 11;
    int a = gtid & (NAP - 1);
    bool real = a < NA;

    unsigned int word = real ? cm[gtid] : 0u;
    int mres = (int)(word & 0xFFFFFu);

    unsigned long long msk = __ballot((word >> 20) >= 2u);
    if (msk != 0ull) {
        int base = gtid & ~63;
        int ng = num_gts[b];
        while (msk) {
            int t = __ffsll((long long)msk) - 1;
            msk &= msk - 1;
            int idx = base + t;
            int aa = idx & (NAP - 1);
            float4 pe = ext[idx];
            float areaP = decA[idx];
            float axc, ayc, st;
            anchor_geom(aa, axc, ayc, st);
            bool fcq = (fgw[(size_t)b * 32 + (aa >> 6)] >> (aa & 63)) & 1ULL;
            unsigned int best = 0xFFFFFFFFu;
#pragma unroll
            for (int half = 0; half < 2; half++) {
                int m = half * 64 + lane;
                if (m < ng) {
                    float4 g = ((const float4*)gt_boxes)[b * NM + m];
                    g.x *= 640.0f; g.y *= 640.0f; g.z *= 640.0f; g.w *= 640.0f;
                    int tcm = gt_classes[b * NM + m];
                    float clsc = qq[((size_t)b * NC + tcm) * NAP + aa];
                    float cc = cost_row(g, clsc, pe, areaP, axc, ayc, st, fcq);
                    unsigned int key = (__float_as_uint(cc) & 0xFFFFF800u) | (unsigned)m;
                    best = min(best, key);
                }
            }
#pragma unroll
            for (int o = 1; o < 64; o <<= 1) {
                unsigned int ov = (unsigned int)__shfl_xor((int)best, o);
                best = min(best, ov);
            }
            if (lane == t) mres = (int)(best & 0x7FFu);
        }
    }

    float lobj = 0.0f, liou = 0.0f, lcls = 0.0f, fgf = 0.0f;
    if (real) {
        float objv;
        if (a < NA0) objv = l0[((size_t)b * 25 + 4) * NA0 + a];
        else         objv = l1[((size_t)b * 25 + 4) * 400 + (a - NA0)];
        bool fg = (word >> 20) > 0;
        fgf = fg ? 1.0f : 0.0f;
        lobj = (fmaxf(objv, 0.0f) + log1pf(expf(-fabsf(objv)))) - objv * fgf;
        if (fg) {
            float4 pe = ext[gtid];
            float areaP = decA[gtid];
            int m = mres;
            float4 g = ((const float4*)gt_boxes)[b * NM + m];
            g.x *= 640.0f; g.y *= 640.0f; g.z *= 640.0f; g.w *= 640.0f;
            float tlx = fmaxf(pe.x, g.x - 0.5f * g.z);
            float tly = fmaxf(pe.z, g.y - 0.5f * g.w);
            float brx = fminf(pe.y, g.x + 0.5f * g.z);
            float bry = fminf(pe.w, g.y + 0.5f * g.w);
            float inter = (brx - tlx) * (bry - tly);
            bool ok = (tlx < brx) && (tly < bry);
            inter = ok ? inter : 0.0f;
            float iou = inter / ((areaP + g.z * g.w) - inter + 1e-16f);
            liou = 1.0f - iou * iou;
            float piou = iou;
            int tcm = gt_classes[b * NM + m];
            float x_t;
            if (a < NA0) x_t = l0[((size_t)b * 25 + 5 + tcm) * NA0 + a];
            else         x_t = l1[((size_t)b * 25 + 5 + tcm) * 400 + (a - NA0)];
            lcls = sp[gtid] - x_t * piou;   // sum_c softplus(x_c) - x_tcm * pred_iou
        }
    }

    __shared__ float s0[256], s1[256], s2[256], s3[256];
    int t = threadIdx.x;
    s0[t] = lobj; s1[t] = liou; s2[t] = lcls; s3[t] = fgf;
    __syncthreads();
    for (int o = 128; o > 0; o >>= 1) {
        if (t < o) { s0[t] += s0[t + o]; s1[t] += s1[t + o]; s2[t] += s2[t + o]; s3[t] += s3[t + o]; }
        __syncthreads();
    }
    if (t == 0) {
        partials[blockIdx.x * 4 + 0] = s0[0];
        partials[blockIdx.x * 4 + 1] = s1[0];
        partials[blockIdx.x * 4 + 2] = s2[0];
        partials[blockIdx.x * 4 + 3] = s3[0];
    }
}

__global__ __launch_bounds__(256) void k_final(const float* __restrict__ partials, int nblocks,
                                               const int* __restrict__ num_gts, float* __restrict__ out) {
    __shared__ float s0[256], s1[256], s2[256], s3[256];
    int t = threadIdx.x;
    float a0 = 0, a1 = 0, a2 = 0, a3 = 0;
    for (int i = t; i < nblocks; i += 256) {
        a0 += partials[i * 4 + 0];
        a1 += partials[i * 4 + 1];
        a2 += partials[i * 4 + 2];
        a3 += partials[i * 4 + 3];
    }
    s0[t] = a0; s1[t] = a1; s2[t] = a2; s3[t] = a3;
    __syncthreads();
    for (int o = 128; o > 0; o >>= 1) {
        if (t < o) { s0[t] += s0[t + o]; s1[t] += s1[t + o]; s2[t] += s2[t + o]; s3[t] += s3[t + o]; }
        __syncthreads();
    }
    if (t == 0) {
        int sg = 0;
        for (int i = 0; i < NB; i++) sg += num_gts[i];
        float num_fg = fmaxf(s3[0], 1.0f);
        float li5 = 5.0f * (s1[0] / num_fg);
        float lo = s0[0] / num_fg;
        float lcx = s2[0] / num_fg;
        out[0] = li5 + lo + lcx;
        out[1] = li5;
        out[2] = lo;
        out[3] = lcx;
        out[4] = num_fg / fmaxf((float)sg, 1.0f);
    }
}

extern "C" void kernel_launch(void* const* d_in, const int* in_sizes, int n_in,
                              void* d_out, int out_size, void* d_ws, size_t ws_size,
                              hipStream_t stream) {
    const float* l0 = (const float*)d_in[0];
    const float* l1 = (const float*)d_in[1];
    const float* gt_boxes = (const float*)d_in[2];
    const int* gt_classes = (const int*)d_in[3];
    const int* num_gts = (const int*)d_in[4];
    float* out = (float*)d_out;

    char* w = (char*)d_ws;
    float4* ext  = (float4*)(w);                           // 64*2048*16 = 2,097,152
    float* decA  = (float*)(w + 2097152);                  // 64*2048*4 = 524,288
    float* qq    = (float*)(w + 2621440);                  // 64*20*2048*4 = 10,485,760
    unsigned long long* fgw = (unsigned long long*)(w + 13107200); // 16,384
    unsigned int* cm = (unsigned int*)(w + 13123584);      // 64*2048*4 = 524,288
    float* sp    = (float*)(w + 13647872);                 // 64*2048*4 = 524,288
    float* partials = (float*)(w + 14172160);              // 512*4*4 = 8,192

    (void)n_in; (void)in_sizes; (void)out_size; (void)ws_size;

    k_decode<<<dim3(8, NB), 256, 0, stream>>>(l0, l1, gt_boxes, num_gts, ext, decA, qq, fgw, cm, sp);
    k_assign<<<(NB * NM) / 2, 256, 0, stream>>>(gt_boxes, gt_classes, num_gts, ext, decA, qq, fgw, cm);
    k_resolve<<<(NB * NAP) / 256, 256, 0, stream>>>(l0, l1, gt_boxes, gt_classes, num_gts, ext, decA, qq, fgw, cm, sp, partials);
    k_final<<<1, 256, 0, stream>>>(partials, (NB * NAP) / 256, num_gts, out);
}